// Round 8
// baseline (753.821 us; speedup 1.0000x reference)
//
#include <hip/hip_runtime.h>
#include <hip/hip_bf16.h>
#include <math.h>

#define FDIM 512
#define NEXP 4
#define HDIM 256
#define ADIM 32
#define BM   256
#define NTHR 512

typedef __attribute__((ext_vector_type(8))) short frag8;   // 8 bf16 (4 VGPR)
typedef __attribute__((ext_vector_type(4))) float f32x4;

// ws layout (ushort elements)
#define W1T_OFF 0                        // [4][256][512]  n-major (col stride 1KB)
#define W2T_OFF (4*256*512)              // [4][32][256]   a-major (col stride 512B)
#define WGT_OFF (W2T_OFF + 4*32*256)     // [16][512]      rows 4..15 zero

__device__ inline ushort f2bf(float x) {
    union { float f; unsigned u; } v; v.f = x;
    unsigned r = v.u + 0x7FFFu + ((v.u >> 16) & 1u);   // RNE
    return (ushort)(r >> 16);
}

__device__ inline frag8 pack8(f32x4 a, f32x4 b) {
    frag8 r;
    r[0] = (short)f2bf(a[0]); r[1] = (short)f2bf(a[1]);
    r[2] = (short)f2bf(a[2]); r[3] = (short)f2bf(a[3]);
    r[4] = (short)f2bf(b[0]); r[5] = (short)f2bf(b[1]);
    r[6] = (short)f2bf(b[2]); r[7] = (short)f2bf(b[3]);
    return r;
}

// async global->LDS, 16B per lane; LDS dest = wave-uniform base + lane*16
__device__ __forceinline__ void gl16(const void* g, void* l) {
    __builtin_amdgcn_global_load_lds(
        (const __attribute__((address_space(1))) unsigned int*)g,
        (__attribute__((address_space(3))) unsigned int*)l, 16, 0, 0);
}

// ---------------- prep: fp32 weights -> transposed bf16 in ws ----------------
__global__ __launch_bounds__(256) void moe_prep(const float* __restrict__ Wg,
                                                const float* __restrict__ W1,
                                                const float* __restrict__ W2,
                                                ushort* __restrict__ ws) {
    const int b = blockIdx.x, t = threadIdx.x;
    if (b < 64) {
        #pragma unroll
        for (int it = 0; it < 4; ++it) {
            int oct = (b * 256 + t) + it * 16384;
            int n = oct & 255, k8 = (oct >> 8) & 63, e = oct >> 14;
            f32x4 v0, v1;
            #pragma unroll
            for (int j = 0; j < 4; ++j) v0[j] = W1[(e*512 + k8*8 + j)*256 + n];
            #pragma unroll
            for (int j = 0; j < 4; ++j) v1[j] = W1[(e*512 + k8*8 + 4 + j)*256 + n];
            *(frag8*)(ws + W1T_OFF + (e*HDIM + n)*FDIM + k8*8) = pack8(v0, v1);
        }
    } else if (b < 80) {
        int oct = (b - 64) * 256 + t;
        int a = oct & 31, n8 = (oct >> 5) & 31, e = oct >> 10;
        f32x4 v0, v1;
        #pragma unroll
        for (int j = 0; j < 4; ++j) v0[j] = W2[(e*HDIM + n8*8 + j)*ADIM + a];
        #pragma unroll
        for (int j = 0; j < 4; ++j) v1[j] = W2[(e*HDIM + n8*8 + 4 + j)*ADIM + a];
        *(frag8*)(ws + W2T_OFF + (e*ADIM + a)*HDIM + n8*8) = pack8(v0, v1);
    } else {
        int oct = (b - 80) * 256 + t;
        int k8 = oct & 63, c = oct >> 6;
        f32x4 v0 = {0,0,0,0}, v1 = {0,0,0,0};
        if (c < NEXP) {
            #pragma unroll
            for (int j = 0; j < 4; ++j) v0[j] = Wg[(k8*8 + j)*NEXP + c];
            #pragma unroll
            for (int j = 0; j < 4; ++j) v1[j] = Wg[(k8*8 + 4 + j)*NEXP + c];
        }
        *(frag8*)(ws + WGT_OFF + c*FDIM + k8*8) = pack8(v0, v1);
    }
}

// ---------------- main fused kernel (v5) ----------------
// R7 post-mortem: LDS-read-throughput bound (9500 b128 reads/block ~= 62us/block
// incl conflicts; MFMA floor 61us whole-chip). LDS B-bytes/FLOP = 1/M_w.
// v5: M_w 16->32 (BM=256, 8 waves x 2 row-tiles): each B-frag ds_read feeds 2
// MFMAs -> GEMM1 LDS reads halve. GEMM2 split per col-half (partial K-sums) so
// hbuf stays 8KB/wave. Gate folded into H (acc2 accumulates across experts).
// LDS: buf0 32K | buf1 32K | w2b 16K | hbuf 64K | wgate 4K = 148KB, 1 blk/CU.
__global__ __launch_bounds__(NTHR, 2) void moe_main(
        const float* __restrict__ feat, const float* __restrict__ bg,
        const float* __restrict__ b1,  const float* __restrict__ b2,
        const ushort* __restrict__ ws, float* __restrict__ out) {
    __shared__ __attribute__((aligned(16))) unsigned char smem[151552];
    unsigned char* buf0 = smem;                     // 32KB granule (even chunks)
    unsigned char* buf1 = smem + 32768;             // 32KB granule (odd) / Wgt at gate
    unsigned char* w2b  = smem + 65536;             // 16KB current expert W2
    unsigned char* hbuf = smem + 81920;             // 64KB H (8KB per wave)
    float*         wgate = (float*)(smem + 147456); // 256 rows x 4 gates

    const int tid = threadIdx.x;
    const int lane = tid & 63;
    const int wave = tid >> 6;        // 0..7
    const int l15 = lane & 15;
    const int lg  = lane >> 4;        // 0..3
    const int row0 = blockIdx.x * BM;
    const int wrow = row0 + wave * 32;              // wave owns 32 rows
    const char* w1b = (const char*)(ws + W1T_OFF);
    const char* w2g = (const char*)(ws + W2T_OFF);
    const char* wgb = (const char*)(ws + WGT_OFF);

    // inverse-swizzled staging source offsets (rule 21)
    int thrOff[4], w2Off[2];
    #pragma unroll
    for (int j = 0; j < 4; ++j) {                  // 32KB granule: [128 col][256B]
        int slot = j * 512 + tid, cl = slot >> 4;
        thrOff[j] = cl * 1024 + (((slot & 15) * 16) ^ ((cl & 7) << 4));
    }
    #pragma unroll
    for (int j = 0; j < 2; ++j) {                  // 16KB W2: [32 col][512B]
        int slot = j * 512 + tid, c2 = slot >> 5;
        w2Off[j] = c2 * 512 + (((slot & 31) * 16) ^ ((c2 & 7) << 4));
    }

    // prologue: stage Wgt -> buf1, granule0 -> buf0
    #pragma unroll
    for (int j = 0; j < 2; ++j) {                  // 16KB Wgt: [16 col][1024B]
        int slot = j * 512 + tid, cg = slot >> 6;
        int gO = cg * 1024 + (((slot & 63) * 16) ^ ((cg & 7) << 4));
        gl16(wgb + gO, buf1 + j * 8192 + wave * 1024);
    }
    #pragma unroll
    for (int j = 0; j < 4; ++j)
        gl16(w1b + thrOff[j], buf0 + j * 8192 + wave * 1024);

    // features -> A-fragments, 2 row-tiles x 16 k-frags (HBM read once)
    frag8 afrag[2][16];
    #pragma unroll
    for (int rt = 0; rt < 2; ++rt) {
        const float* fp = feat + (size_t)(wrow + rt * 16 + l15) * FDIM + lg * 8;
        #pragma unroll
        for (int g4 = 0; g4 < 4; ++g4) {
            f32x4 t0[4], t1[4];
            #pragma unroll
            for (int s = 0; s < 4; ++s) {
                const float* p = fp + (g4 * 4 + s) * 32;
                t0[s] = *(const f32x4*)p;
                t1[s] = *(const f32x4*)(p + 4);
            }
            #pragma unroll
            for (int s = 0; s < 4; ++s) afrag[rt][g4 * 4 + s] = pack8(t0[s], t1[s]);
        }
    }

    __syncthreads();   // Wgt + granule0 resident

    // ---- gate (reads buf1): one B-read feeds both row-tiles ----
    {
        f32x4 ga[2];
        ga[0] = (f32x4){0.f,0.f,0.f,0.f}; ga[1] = (f32x4){0.f,0.f,0.f,0.f};
        #pragma unroll
        for (int s = 0; s < 16; ++s) {
            frag8 bb = *(const frag8*)(buf1 + l15 * 1024 + ((s * 64 + lg * 16) ^ ((l15 & 7) << 4)));
            ga[0] = __builtin_amdgcn_mfma_f32_16x16x32_bf16(afrag[0][s], bb, ga[0], 0, 0, 0);
            ga[1] = __builtin_amdgcn_mfma_f32_16x16x32_bf16(afrag[1][s], bb, ga[1], 0, 0, 0);
        }
        float bgv = bg[l15 & 3];
        #pragma unroll
        for (int rt = 0; rt < 2; ++rt)
            #pragma unroll
            for (int r = 0; r < 4; ++r) {
                float v = ga[rt][r] + bgv;
                float m = fmaxf(v, __shfl_xor(v, 1));
                m = fmaxf(m, __shfl_xor(m, 2));
                float eV = expf(v - m);
                float sV = eV + __shfl_xor(eV, 1);
                sV += __shfl_xor(sV, 2);
                if (l15 < NEXP) wgate[(wave * 32 + rt * 16 + lg * 4 + r) * 4 + l15] = eV / sV;
            }
    }
    __syncthreads();   // buf1 free; wgate visible

    f32x4 acc2[2][2];  // gated output accumulator, persists across experts+halves
    #pragma unroll
    for (int rt = 0; rt < 2; ++rt)
        #pragma unroll
        for (int c2 = 0; c2 < 2; ++c2) acc2[rt][c2] = (f32x4){0.f,0.f,0.f,0.f};

    for (int e = 0; e < NEXP; ++e) {
        #pragma unroll
        for (int h = 0; h < 2; ++h) {              // col-half of HDIM
            f32x4 acc1[2][8];
            #pragma unroll
            for (int rt = 0; rt < 2; ++rt)
                #pragma unroll
                for (int ct = 0; ct < 8; ++ct) acc1[rt][ct] = (f32x4){0.f,0.f,0.f,0.f};

            #pragma unroll
            for (int c = 0; c < 4; ++c) {          // K-chunks of 128
                const int g = e * 8 + h * 4 + c;
                if (g < 31) {                      // issue next granule BEFORE compute
                    const int gn = g + 1;
                    const char* sb = w1b + (gn >> 2) * 131072 + (gn & 3) * 256;
                    unsigned char* db = (c & 1) ? buf0 : buf1;
                    #pragma unroll
                    for (int j = 0; j < 4; ++j)
                        gl16(sb + thrOff[j], db + j * 8192 + wave * 1024);
                }
                if (h == 0 && c == 1) {            // stage W2[e] (after c0-barrier ->
                    const char* sb2 = w2g + e * 16384;  // GEMM2(e-1) reads all done)
                    #pragma unroll
                    for (int j = 0; j < 2; ++j)
                        gl16(sb2 + w2Off[j], w2b + j * 8192 + wave * 1024);
                }
                const unsigned char* src = (c & 1) ? buf1 : buf0;
                #pragma unroll
                for (int s = 0; s < 4; ++s)
                    #pragma unroll
                    for (int ct = 0; ct < 8; ++ct) {
                        frag8 bb = *(const frag8*)(src + (ct * 16 + l15) * 256 +
                                                   ((s * 64 + lg * 16) ^ ((l15 & 7) << 4)));
                        acc1[0][ct] = __builtin_amdgcn_mfma_f32_16x16x32_bf16(
                            afrag[0][c * 4 + s], bb, acc1[0][ct], 0, 0, 0);
                        acc1[1][ct] = __builtin_amdgcn_mfma_f32_16x16x32_bf16(
                            afrag[1][c * 4 + s], bb, acc1[1][ct], 0, 0, 0);
                    }
                __syncthreads();
            }

            // H-half = gate * relu(acc1 + b1) -> per-wave LDS (swizzled, row stride 256B)
            unsigned char* hb = hbuf + wave * 8192;
            float b1v[8];
            #pragma unroll
            for (int ct = 0; ct < 8; ++ct) b1v[ct] = b1[e * HDIM + h * 128 + ct * 16 + l15];
            #pragma unroll
            for (int rt = 0; rt < 2; ++rt)
                #pragma unroll
                for (int r = 0; r < 4; ++r) {
                    int row = rt * 16 + lg * 4 + r;
                    float gt = wgate[(wave * 32 + row) * 4 + e];
                    #pragma unroll
                    for (int ct = 0; ct < 8; ++ct) {
                        float v = fmaxf(acc1[rt][ct][r] + b1v[ct], 0.f) * gt;
                        *(ushort*)(hb + row * 256 + (((ct * 16 + l15) * 2) ^ ((row & 7) << 4))) = f2bf(v);
                    }
                }
            asm volatile("s_waitcnt lgkmcnt(0)" ::: "memory");   // own H writes visible
            __builtin_amdgcn_sched_barrier(0);                   // rule 18

            // GEMM2 partial (K-half h): acc2 += H_half x W2_half
            #pragma unroll
            for (int s2 = 0; s2 < 4; ++s2) {
                frag8 ha0 = *(const frag8*)(hb + l15 * 256 +
                                            ((s2 * 64 + lg * 16) ^ ((l15 & 7) << 4)));
                frag8 ha1 = *(const frag8*)(hb + (16 + l15) * 256 +
                                            ((s2 * 64 + lg * 16) ^ ((l15 & 7) << 4)));
                #pragma unroll
                for (int ct2 = 0; ct2 < 2; ++ct2) {
                    frag8 bb = *(const frag8*)(w2b + (ct2 * 16 + l15) * 512 + h * 256 +
                                               ((s2 * 64 + lg * 16) ^ ((l15 & 7) << 4)));
                    acc2[0][ct2] = __builtin_amdgcn_mfma_f32_16x16x32_bf16(ha0, bb, acc2[0][ct2], 0, 0, 0);
                    acc2[1][ct2] = __builtin_amdgcn_mfma_f32_16x16x32_bf16(ha1, bb, acc2[1][ct2], 0, 0, 0);
                }
            }
        }
    }

    // ---- epilogue: + sum_e gate_e * b2[e], store 32 rows x 32 cols per wave ----
    #pragma unroll
    for (int ct2 = 0; ct2 < 2; ++ct2) {
        int col = ct2 * 16 + l15;
        float b2v0 = b2[col], b2v1 = b2[32 + col], b2v2 = b2[64 + col], b2v3 = b2[96 + col];
        #pragma unroll
        for (int rt = 0; rt < 2; ++rt)
            #pragma unroll
            for (int r = 0; r < 4; ++r) {
                int rl = wave * 32 + rt * 16 + lg * 4 + r;
                f32x4 gv = *(const f32x4*)(wgate + rl * 4);
                float bs = gv[0]*b2v0 + gv[1]*b2v1 + gv[2]*b2v2 + gv[3]*b2v3;
                out[(size_t)(row0 + rl) * ADIM + col] = acc2[rt][ct2][r] + bs;
            }
    }
}

extern "C" void kernel_launch(void* const* d_in, const int* in_sizes, int n_in,
                              void* d_out, int out_size, void* d_ws, size_t ws_size,
                              hipStream_t stream) {
    const float* feat = (const float*)d_in[0];
    const float* Wg   = (const float*)d_in[1];
    const float* bg   = (const float*)d_in[2];
    const float* W1   = (const float*)d_in[3];
    const float* b1   = (const float*)d_in[4];
    const float* W2   = (const float*)d_in[5];
    const float* b2   = (const float*)d_in[6];
    float* out = (float*)d_out;
    ushort* ws = (ushort*)d_ws;

    moe_prep<<<84, 256, 0, stream>>>(Wg, W1, W2, ws);
    const int nblk = 131072 / BM;   // 512
    moe_main<<<nblk, NTHR, 0, stream>>>(feat, bg, b1, b2, ws, out);
}

// Round 10
// 633.091 us; speedup vs baseline: 1.1907x; 1.1907x over previous
//
#include <hip/hip_runtime.h>
#include <hip/hip_bf16.h>
#include <math.h>

#define FDIM 512
#define NEXP 4
#define HDIM 256
#define ADIM 32
#define BM   256
#define NTHR 512

typedef __attribute__((ext_vector_type(8))) short frag8;   // 8 bf16 (4 VGPR)
typedef __attribute__((ext_vector_type(4))) float f32x4;

// ws layout (ushort elements)
#define W1T_OFF 0                        // [4][256][512]  n-major (col stride 1KB)
#define W2T_OFF (4*256*512)              // [4][32][256]   a-major (col stride 512B)
#define WGT_OFF (W2T_OFF + 4*32*256)     // [16][512]      rows 4..15 zero

__device__ inline ushort f2bf(float x) {
    union { float f; unsigned u; } v; v.f = x;
    unsigned r = v.u + 0x7FFFu + ((v.u >> 16) & 1u);   // RNE
    return (ushort)(r >> 16);
}

__device__ inline frag8 pack8(f32x4 a, f32x4 b) {
    frag8 r;
    r[0] = (short)f2bf(a[0]); r[1] = (short)f2bf(a[1]);
    r[2] = (short)f2bf(a[2]); r[3] = (short)f2bf(a[3]);
    r[4] = (short)f2bf(b[0]); r[5] = (short)f2bf(b[1]);
    r[6] = (short)f2bf(b[2]); r[7] = (short)f2bf(b[3]);
    return r;
}

// pack two f32 -> {bf16(lo), bf16(hi)} in one u32 (RNE); no builtin on gfx950
__device__ __forceinline__ unsigned cvtpk(float lo, float hi) {
    unsigned r;
    asm volatile("v_cvt_pk_bf16_f32 %0, %1, %2" : "=v"(r) : "v"(lo), "v"(hi));
    return r;
}

// async global->LDS, 16B per lane; LDS dest = wave-uniform base + lane*16
__device__ __forceinline__ void gl16(const void* g, void* l) {
    __builtin_amdgcn_global_load_lds(
        (const __attribute__((address_space(1))) unsigned int*)g,
        (__attribute__((address_space(3))) unsigned int*)l, 16, 0, 0);
}

// ---------------- prep: fp32 weights -> transposed bf16 in ws ----------------
__global__ __launch_bounds__(256) void moe_prep(const float* __restrict__ Wg,
                                                const float* __restrict__ W1,
                                                const float* __restrict__ W2,
                                                ushort* __restrict__ ws) {
    const int b = blockIdx.x, t = threadIdx.x;
    if (b < 64) {
        #pragma unroll
        for (int it = 0; it < 4; ++it) {
            int oct = (b * 256 + t) + it * 16384;
            int n = oct & 255, k8 = (oct >> 8) & 63, e = oct >> 14;
            f32x4 v0, v1;
            #pragma unroll
            for (int j = 0; j < 4; ++j) v0[j] = W1[(e*512 + k8*8 + j)*256 + n];
            #pragma unroll
            for (int j = 0; j < 4; ++j) v1[j] = W1[(e*512 + k8*8 + 4 + j)*256 + n];
            *(frag8*)(ws + W1T_OFF + (e*HDIM + n)*FDIM + k8*8) = pack8(v0, v1);
        }
    } else if (b < 80) {
        int oct = (b - 64) * 256 + t;
        int a = oct & 31, n8 = (oct >> 5) & 31, e = oct >> 10;
        f32x4 v0, v1;
        #pragma unroll
        for (int j = 0; j < 4; ++j) v0[j] = W2[(e*HDIM + n8*8 + j)*ADIM + a];
        #pragma unroll
        for (int j = 0; j < 4; ++j) v1[j] = W2[(e*HDIM + n8*8 + 4 + j)*ADIM + a];
        *(frag8*)(ws + W2T_OFF + (e*ADIM + a)*HDIM + n8*8) = pack8(v0, v1);
    } else {
        int oct = (b - 80) * 256 + t;
        int k8 = oct & 63, c = oct >> 6;
        f32x4 v0 = {0,0,0,0}, v1 = {0,0,0,0};
        if (c < NEXP) {
            #pragma unroll
            for (int j = 0; j < 4; ++j) v0[j] = Wg[(k8*8 + j)*NEXP + c];
            #pragma unroll
            for (int j = 0; j < 4; ++j) v1[j] = Wg[(k8*8 + 4 + j)*NEXP + c];
        }
        *(frag8*)(ws + WGT_OFF + c*FDIM + k8*8) = pack8(v0, v1);
    }
}

// ---------------- main fused kernel (v6) ----------------
// R8 post-mortem: v5's M_w=32 never ran unspilled (VGPR capped 128, demand ~240;
// WRITE_SIZE 442MB scratch). v6: (a) amdgpu_waves_per_eu(2,2) forces the 256-reg
// allocation (2 waves/SIMD x 256 = full unified file; m08: no spill <450);
// (b) GEMM1 operands FLIPPED (A=W1 from LDS, B=features in regs -- identical frag
// layout, afrag reused): C gives lane=frow, regs=4 consecutive h -> H written as
// b64 (cvt_pk x2), 32 writes/wave/expert vs 128 scalar; GEMM2 reads H row-major
// b128 2-way-free. B-reads stay halved vs R7 (M_w=32).
// LDS: buf0 32K | buf1 32K | w2b 16K | hbuf 64K | wgate 4K = 148KB, 1 blk/CU.
__global__ __attribute__((amdgpu_waves_per_eu(2, 2))) __launch_bounds__(NTHR)
void moe_main(
        const float* __restrict__ feat, const float* __restrict__ bg,
        const float* __restrict__ b1,  const float* __restrict__ b2,
        const ushort* __restrict__ ws, float* __restrict__ out) {
    __shared__ __attribute__((aligned(16))) unsigned char smem[151552];
    unsigned char* buf0 = smem;                     // 32KB granule (even chunks)
    unsigned char* buf1 = smem + 32768;             // 32KB granule (odd) / Wgt at gate
    unsigned char* w2b  = smem + 65536;             // 16KB current expert W2
    unsigned char* hbuf = smem + 81920;             // 64KB H (8KB per wave)
    float*         wgate = (float*)(smem + 147456); // 256 rows x 4 gates

    const int tid = threadIdx.x;
    const int lane = tid & 63;
    const int wave = tid >> 6;        // 0..7
    const int l15 = lane & 15;
    const int lg  = lane >> 4;        // 0..3
    const int row0 = blockIdx.x * BM;
    const int wrow = row0 + wave * 32;              // wave owns 32 rows
    const char* w1b = (const char*)(ws + W1T_OFF);
    const char* w2g = (const char*)(ws + W2T_OFF);
    const char* wgb = (const char*)(ws + WGT_OFF);
    const int swz = (l15 & 7) << 4;                 // row/col XOR swizzle

    // inverse-swizzled staging source offsets (rule 21)
    int thrOff[4], w2Off[2];
    #pragma unroll
    for (int j = 0; j < 4; ++j) {                  // 32KB granule: [128 col][256B]
        int slot = j * 512 + tid, cl = slot >> 4;
        thrOff[j] = cl * 1024 + (((slot & 15) * 16) ^ ((cl & 7) << 4));
    }
    #pragma unroll
    for (int j = 0; j < 2; ++j) {                  // 16KB W2: [32 col][512B]
        int slot = j * 512 + tid, c2 = slot >> 5;
        w2Off[j] = c2 * 512 + (((slot & 31) * 16) ^ ((c2 & 7) << 4));
    }

    // prologue: stage Wgt -> buf1, granule0 -> buf0
    #pragma unroll
    for (int j = 0; j < 2; ++j) {                  // 16KB Wgt: [16 col][1024B]
        int slot = j * 512 + tid, cg = slot >> 6;
        int gO = cg * 1024 + (((slot & 63) * 16) ^ ((cg & 7) << 4));
        gl16(wgb + gO, buf1 + j * 8192 + wave * 1024);
    }
    #pragma unroll
    for (int j = 0; j < 4; ++j)
        gl16(w1b + thrOff[j], buf0 + j * 8192 + wave * 1024);

    // features -> fragments, 2 row-tiles x 16 k-frags (HBM read once)
    frag8 afrag[2][16];
    #pragma unroll
    for (int rt = 0; rt < 2; ++rt) {
        const float* fp = feat + (size_t)(wrow + rt * 16 + l15) * FDIM + lg * 8;
        #pragma unroll
        for (int g4 = 0; g4 < 4; ++g4) {
            f32x4 t0[4], t1[4];
            #pragma unroll
            for (int s = 0; s < 4; ++s) {
                const float* p = fp + (g4 * 4 + s) * 32;
                t0[s] = *(const f32x4*)p;
                t1[s] = *(const f32x4*)(p + 4);
            }
            #pragma unroll
            for (int s = 0; s < 4; ++s) afrag[rt][g4 * 4 + s] = pack8(t0[s], t1[s]);
        }
    }

    __syncthreads();   // Wgt + granule0 resident

    // ---- gate (A=afrag, B=Wgt from buf1) + 4-lane-group softmax ----
    {
        f32x4 ga[2];
        ga[0] = (f32x4){0.f,0.f,0.f,0.f}; ga[1] = (f32x4){0.f,0.f,0.f,0.f};
        #pragma unroll
        for (int s = 0; s < 16; ++s) {
            frag8 bb = *(const frag8*)(buf1 + l15 * 1024 + ((s * 64 + lg * 16) ^ swz));
            ga[0] = __builtin_amdgcn_mfma_f32_16x16x32_bf16(afrag[0][s], bb, ga[0], 0, 0, 0);
            ga[1] = __builtin_amdgcn_mfma_f32_16x16x32_bf16(afrag[1][s], bb, ga[1], 0, 0, 0);
        }
        float bgv = bg[l15 & 3];
        #pragma unroll
        for (int rt = 0; rt < 2; ++rt)
            #pragma unroll
            for (int r = 0; r < 4; ++r) {
                float v = ga[rt][r] + bgv;
                float m = fmaxf(v, __shfl_xor(v, 1));
                m = fmaxf(m, __shfl_xor(m, 2));
                float eV = expf(v - m);
                float sV = eV + __shfl_xor(eV, 1);
                sV += __shfl_xor(sV, 2);
                if (l15 < NEXP) wgate[(wave * 32 + rt * 16 + lg * 4 + r) * 4 + l15] = eV / sV;
            }
    }
    __syncthreads();   // buf1 free; wgate visible

    f32x4 acc2[2][2];  // [rt][ct2] output accumulator across experts+halves
    #pragma unroll
    for (int rt = 0; rt < 2; ++rt)
        #pragma unroll
        for (int c2 = 0; c2 < 2; ++c2) acc2[rt][c2] = (f32x4){0.f,0.f,0.f,0.f};

    for (int e = 0; e < NEXP; ++e) {
        float gt0 = wgate[(wave * 32 + l15) * 4 + e];        // rt=0 frow gate
        float gt1 = wgate[(wave * 32 + 16 + l15) * 4 + e];   // rt=1
        #pragma unroll
        for (int h = 0; h < 2; ++h) {              // col-half of HDIM
            f32x4 acc1[8][2];                      // [h-tile ct][frow-tile rt]
            #pragma unroll
            for (int ct = 0; ct < 8; ++ct)
                #pragma unroll
                for (int rt = 0; rt < 2; ++rt) acc1[ct][rt] = (f32x4){0.f,0.f,0.f,0.f};

            #pragma unroll
            for (int c = 0; c < 4; ++c) {          // K-chunks of 128
                const int g = e * 8 + h * 4 + c;
                if (g < 31) {                      // issue next granule BEFORE compute
                    const int gn = g + 1;
                    const char* sb = w1b + (gn >> 2) * 131072 + (gn & 3) * 256;
                    unsigned char* db = (c & 1) ? buf0 : buf1;
                    #pragma unroll
                    for (int j = 0; j < 4; ++j)
                        gl16(sb + thrOff[j], db + j * 8192 + wave * 1024);
                }
                if (h == 0 && c == 1) {            // stage W2[e] (c0-barrier passed ->
                    const char* sb2 = w2g + e * 16384;  // GEMM2(e-1) reads all done)
                    #pragma unroll
                    for (int j = 0; j < 2; ++j)
                        gl16(sb2 + w2Off[j], w2b + j * 8192 + wave * 1024);
                }
                const unsigned char* src = (c & 1) ? buf1 : buf0;
                #pragma unroll
                for (int s = 0; s < 4; ++s)
                    #pragma unroll
                    for (int ct = 0; ct < 8; ++ct) {
                        frag8 aw = *(const frag8*)(src + (ct * 16 + l15) * 256 +
                                                   ((s * 64 + lg * 16) ^ swz));
                        acc1[ct][0] = __builtin_amdgcn_mfma_f32_16x16x32_bf16(
                            aw, afrag[0][c * 4 + s], acc1[ct][0], 0, 0, 0);
                        acc1[ct][1] = __builtin_amdgcn_mfma_f32_16x16x32_bf16(
                            aw, afrag[1][c * 4 + s], acc1[ct][1], 0, 0, 0);
                    }
                __syncthreads();
            }

            // H-half = gate * relu(acc1 + b1): lane=frow, regs=4 consecutive h
            // -> cvt_pk x2 + single b64 write per (ct,rt)
            unsigned char* hb = hbuf + wave * 8192;   // [32 frow][128 h] row stride 256B
            #pragma unroll
            for (int ct = 0; ct < 8; ++ct) {
                f32x4 b1q = *(const f32x4*)(b1 + e * HDIM + h * 128 + ct * 16 + lg * 4);
                #pragma unroll
                for (int rt = 0; rt < 2; ++rt) {
                    float gt = rt ? gt1 : gt0;
                    float v0 = fmaxf(acc1[ct][rt][0] + b1q[0], 0.f) * gt;
                    float v1 = fmaxf(acc1[ct][rt][1] + b1q[1], 0.f) * gt;
                    float v2 = fmaxf(acc1[ct][rt][2] + b1q[2], 0.f) * gt;
                    float v3 = fmaxf(acc1[ct][rt][3] + b1q[3], 0.f) * gt;
                    uint2 u;
                    u.x = cvtpk(v0, v1);
                    u.y = cvtpk(v2, v3);
                    *(uint2*)(hb + (rt * 16 + l15) * 256 +
                              ((ct * 32 + lg * 8) ^ swz)) = u;
                }
            }
            asm volatile("s_waitcnt lgkmcnt(0)" ::: "memory");   // own H writes visible
            __builtin_amdgcn_sched_barrier(0);                   // rule 18

            // GEMM2 partial (K-half h): acc2 += H_half x W2_half (A=H row-major b128)
            #pragma unroll
            for (int s2 = 0; s2 < 4; ++s2) {
                frag8 ha0 = *(const frag8*)(hb + l15 * 256 + ((s2 * 64 + lg * 16) ^ swz));
                frag8 ha1 = *(const frag8*)(hb + (16 + l15) * 256 + ((s2 * 64 + lg * 16) ^ swz));
                #pragma unroll
                for (int ct2 = 0; ct2 < 2; ++ct2) {
                    frag8 bb = *(const frag8*)(w2b + (ct2 * 16 + l15) * 512 + h * 256 +
                                               ((s2 * 64 + lg * 16) ^ swz));
                    acc2[0][ct2] = __builtin_amdgcn_mfma_f32_16x16x32_bf16(ha0, bb, acc2[0][ct2], 0, 0, 0);
                    acc2[1][ct2] = __builtin_amdgcn_mfma_f32_16x16x32_bf16(ha1, bb, acc2[1][ct2], 0, 0, 0);
                }
            }
        }
    }

    // ---- epilogue: + sum_e gate_e * b2[e], store 32 rows x 32 cols per wave ----
    #pragma unroll
    for (int ct2 = 0; ct2 < 2; ++ct2) {
        int col = ct2 * 16 + l15;
        float b2v0 = b2[col], b2v1 = b2[32 + col], b2v2 = b2[64 + col], b2v3 = b2[96 + col];
        #pragma unroll
        for (int rt = 0; rt < 2; ++rt)
            #pragma unroll
            for (int r = 0; r < 4; ++r) {
                int rl = wave * 32 + rt * 16 + lg * 4 + r;
                f32x4 gv = *(const f32x4*)(wgate + rl * 4);
                float bs = gv[0]*b2v0 + gv[1]*b2v1 + gv[2]*b2v2 + gv[3]*b2v3;
                out[(size_t)(row0 + rl) * ADIM + col] = acc2[rt][ct2][r] + bs;
            }
    }
}

extern "C" void kernel_launch(void* const* d_in, const int* in_sizes, int n_in,
                              void* d_out, int out_size, void* d_ws, size_t ws_size,
                              hipStream_t stream) {
    const float* feat = (const float*)d_in[0];
    const float* Wg   = (const float*)d_in[1];
    const float* bg   = (const float*)d_in[2];
    const float* W1   = (const float*)d_in[3];
    const float* b1   = (const float*)d_in[4];
    const float* W2   = (const float*)d_in[5];
    const float* b2   = (const float*)d_in[6];
    float* out = (float*)d_out;
    ushort* ws = (ushort*)d_ws;

    moe_prep<<<84, 256, 0, stream>>>(Wg, W1, W2, ws);
    const int nblk = 131072 / BM;   // 512
    moe_main<<<nblk, NTHR, 0, stream>>>(feat, bg, b1, b2, ws, out);
}